// Round 15
// baseline (295.883 us; speedup 1.0000x reference)
//
#include <hip/hip_runtime.h>
#include <hip/hip_bf16.h>
#include <math.h>
#include <string.h>

#define BATCH   4
#define SEQ     2044
#define DMODEL  512
#define DINNER  1024
#define NHEADS  16
#define HEADDIM 64
#define DSTATE  64
#define CONVDIM 1152
#define DINPROJ 2192
#define ZW      2176          // bf16-stored width of zxbcdt (z + xBC); dt cols -> fp32 lab
#define NROWS   (BATCH*SEQ)   // 8176
#define Q       64
#define NCHUNK  32

typedef __attribute__((ext_vector_type(8))) short bf16x8;
typedef __attribute__((ext_vector_type(4))) short short4v;
typedef __attribute__((ext_vector_type(4))) float f32x4;

#define MFMA(a,b,c) __builtin_amdgcn_mfma_f32_16x16x32_bf16((a),(b),(c),0,0,0)

__device__ inline short f2bf(float f) {
    __hip_bfloat16 h = __float2bfloat16(f);
    short s; memcpy(&s, &h, 2); return s;
}
__device__ inline float bf2f(short s) {
    unsigned u = ((unsigned)(unsigned short)s) << 16;
    float f; memcpy(&f, &u, 4); return f;
}
__device__ inline float bf2f_lo(unsigned u) {
    unsigned v = u << 16; float f; memcpy(&f, &v, 4); return f;
}
__device__ inline float bf2f_hi(unsigned u) {
    unsigned v = u & 0xffff0000u; float f; memcpy(&f, &v, 4); return f;
}

// async global->LDS, 16B per lane; LDS dest = wave-uniform base + lane*16
__device__ __forceinline__ void gload16(const short* g, short* l) {
    __builtin_amdgcn_global_load_lds(
        (const __attribute__((address_space(1))) void*)g,
        (__attribute__((address_space(3))) void*)l, 16, 0, 0);
}

// ---------------- elementwise fp32 -> bf16 convert (8/thread) ----------------
__global__ __launch_bounds__(256) void convert_bf16_kernel(const float* __restrict__ in,
                                                           short* __restrict__ out, int n8) {
    int i = blockIdx.x * 256 + threadIdx.x;
    if (i >= n8) return;
    float4 v0 = *((const float4*)in + i * 2);
    float4 v1 = *((const float4*)in + i * 2 + 1);
    short t[8];
    t[0]=f2bf(v0.x); t[1]=f2bf(v0.y); t[2]=f2bf(v0.z); t[3]=f2bf(v0.w);
    t[4]=f2bf(v1.x); t[5]=f2bf(v1.y); t[6]=f2bf(v1.z); t[7]=f2bf(v1.w);
    *((bf16x8*)out + i) = *(const bf16x8*)t;
}

// ------- transpose + convert: in fp32 [R][ldi] -> out bf16 [Cc][R] -------
__global__ __launch_bounds__(256) void transpose_cvt_kernel(const float* __restrict__ in,
                                                            short* __restrict__ out,
                                                            int R, int Cc, int ldi) {
    __shared__ float tile[64][65];
    const int bx = blockIdx.x * 64;
    const int by = blockIdx.y * 64;
    const int tid = threadIdx.x;
#pragma unroll
    for (int i = 0; i < 16; i++) {
        int idx = tid + i * 256; int r = idx >> 6, c = idx & 63;
        float v = 0.f;
        if (by + r < R && bx + c < Cc) v = in[(size_t)(by + r) * ldi + bx + c];
        tile[r][c] = v;
    }
    __syncthreads();
#pragma unroll
    for (int i = 0; i < 16; i++) {
        int idx = tid + i * 256; int c = idx >> 6, r = idx & 63;
        if (bx + c < Cc && by + r < R)
            out[(size_t)(bx + c) * R + by + r] = f2bf(tile[r][c]);
    }
}

// ---- bf16 MFMA GEMM, 64x64 tile, BK=64: A via gload_lds+swizzle, B streamed from L2 ----
// A LDS [64][64] shorts (8 KB), 16B slot s of row r holds global col16 (s ^ (r&7)).
// B fragments loaded per-lane directly from global (weights are L2-resident):
//   lane needs Bt[(bn + j*16 + lane15)*K + kk + kgrp*8], contiguous 16B -> dwordx4.
// Per wave per K-step: 2 gload16 (A), 8 global b128 (B), 2 ds_read (A), 8 MFMA.
// Epilogue: cols >= Nbf get softplus(v+dt_bias)*(-exp(A_log)) written fp32 to dtout (fused la).
template<bool BF16OUT>
__global__ __launch_bounds__(256) void gemm_bf16(const short* __restrict__ A,
                                                 const short* __restrict__ Bt,
                                                 void* __restrict__ Cv,
                                                 int M, int N, int K,
                                                 int Nbf, float* __restrict__ dtout,
                                                 const float* __restrict__ dt_bias,
                                                 const float* __restrict__ A_log) {
    __shared__ short As[64][64];
    const int tid = threadIdx.x;
    const int wave = tid >> 6, lane = tid & 63;
    const int bm = blockIdx.x * 64, bn = blockIdx.y * 64;
    const int lane15 = lane & 15;
    const int kgrp = lane >> 4;               // 0..3: which 8-short k-chunk
    const int srow = lane >> 3;               // 0..7: row within 8-row DMA group
    const int scol = (lane & 7) ^ srow;       // pre-swizzled source 16B slot
    const int r7 = lane15 & 7;

    f32x4 acc[4];
#pragma unroll
    for (int j = 0; j < 4; j++) acc[j] = (f32x4){0.f, 0.f, 0.f, 0.f};

    // per-lane global sources; wave w stages A rows w*16..w*16+15
    const short* Ab = A + (size_t)(bm + wave * 16 + srow) * K + scol * 8;
    // per-lane B fragment base pointers (direct global)
    const short* Bp[4];
#pragma unroll
    for (int j = 0; j < 4; j++)
        Bp[j] = Bt + (size_t)(bn + j * 16 + lane15) * K + kgrp * 8;

    for (int kk = 0; kk < K; kk += 64) {
        gload16(Ab + kk,                 &As[wave * 16][0]);
        gload16(Ab + 8 * (size_t)K + kk, &As[wave * 16 + 8][0]);
        // B fragments straight from global (L2-hot weights)
        bf16x8 b0[4], b1[4];
#pragma unroll
        for (int j = 0; j < 4; j++) {
            b0[j] = *(const bf16x8*)(Bp[j] + kk);
            b1[j] = *(const bf16x8*)(Bp[j] + kk + 32);
        }
        __syncthreads();   // drains A-DMA and B-loads; tile ready
        const int arow = (wave << 4) + lane15;
        bf16x8 a0 = *(const bf16x8*)&As[arow][(kgrp ^ r7) * 8];
        bf16x8 a1 = *(const bf16x8*)&As[arow][((kgrp + 4) ^ r7) * 8];
#pragma unroll
        for (int j = 0; j < 4; j++) {
            acc[j] = MFMA(a0, b0[j], acc[j]);
            acc[j] = MFMA(a1, b1[j], acc[j]);
        }
        __syncthreads();   // all waves done reading A before next tile overwrites
    }
    const int crow = bm + (wave << 4) + ((lane >> 4) << 2);
    const int ccol0 = bn + lane15;
    const int ndt = N - Nbf;
#pragma unroll
    for (int j = 0; j < 4; j++) {
        int gn = ccol0 + j * 16;
        if (gn >= N) continue;
#pragma unroll
        for (int i = 0; i < 4; i++) {
            int gm = crow + i;
            if (gm >= M) continue;
            float v = acc[j][i];
            if (BF16OUT) {
                if (dtout != nullptr && gn >= Nbf) {
                    int h = gn - Nbf;
                    float v2 = v + dt_bias[h];
                    float sp = (v2 > 20.f) ? v2 : log1pf(expf(v2));
                    dtout[(size_t)gm * ndt + h] = sp * (-expf(A_log[h]));
                } else {
                    ((short*)Cv)[(size_t)gm * Nbf + gn] = f2bf(v);
                }
            } else {
                ((float*)Cv)[(size_t)gm * N + gn] = v;
            }
        }
    }
}

// -------- depthwise causal conv (k=4) + bias + SiLU; 2 channels/thread, 4B loads --------
__global__ __launch_bounds__(256) void conv_silu_kernel(const short* __restrict__ zxb,
                                                        const float* __restrict__ conv_w,
                                                        const float* __restrict__ conv_b,
                                                        short* __restrict__ convo) {
    const int CH2 = CONVDIM / 2;   // 576 channel pairs
    int idx = blockIdx.x * 256 + threadIdx.x;
    if (idx >= BATCH * (SEQ/4) * CH2) return;
    int cpair = idx % CH2;
    int q = idx / CH2;
    int b = q / (SEQ/4);
    int t0 = (q % (SEQ/4)) * 4;
    int c = cpair * 2;
    const size_t base = ((size_t)b * SEQ + t0) * ZW + DINNER + c;
    float4 wv0 = *(const float4*)&conv_w[c * 4];
    float4 wv1 = *(const float4*)&conv_w[c * 4 + 4];
    float x0[7], x1[7];
#pragma unroll
    for (int i = 0; i < 7; i++) {
        int t = t0 - 3 + i;
        if (t >= 0) {
            unsigned u = *(const unsigned*)&zxb[base + (size_t)(i - 3) * ZW];
            x0[i] = bf2f_lo(u); x1[i] = bf2f_hi(u);
        } else { x0[i] = 0.f; x1[i] = 0.f; }
    }
    const float b0 = conv_b[c], b1 = conv_b[c + 1];
    const size_t obase = ((size_t)b * SEQ + t0) * CONVDIM + c;
#pragma unroll
    for (int i = 0; i < 4; i++) {
        float a0 = b0 + x0[i]*wv0.x + x0[i+1]*wv0.y + x0[i+2]*wv0.z + x0[i+3]*wv0.w;
        float a1 = b1 + x1[i]*wv1.x + x1[i+1]*wv1.y + x1[i+2]*wv1.z + x1[i+3]*wv1.w;
        float s0 = a0 / (1.f + expf(-a0));
        float s1 = a1 / (1.f + expf(-a1));
        unsigned o = (unsigned)(unsigned short)f2bf(s0) |
                     ((unsigned)(unsigned short)f2bf(s1) << 16);
        *(unsigned*)&convo[obase + (size_t)i * CONVDIM] = o;
    }
}

// ------------- Phase A: per-(b,chunk,head) chunk state S = (w x)^T B (bf16 out) -------------
__global__ __launch_bounds__(256) void chunk_state_kernel(
    const short* __restrict__ convo,
    const float* __restrict__ lab,
    const float* __restrict__ A_log,
    short* __restrict__ Sbf,
    float* __restrict__ atot)
{
    const int blk = blockIdx.x;
    const int h  = blk & 15;
    const int bc = blk >> 4;
    const int c  = bc & (NCHUNK - 1);
    const int b  = bc >> 5;
    const int t0 = c * Q;
    const int len = min(Q, SEQ - t0);
    const int tid = threadIdx.x;
    const int wave = tid >> 6, lane = tid & 63;
    const size_t rowbase = (size_t)b * SEQ + t0;

    __shared__ short Xt[64][72];    // x^T    [p][s]
    __shared__ short Bw[64][72];    // (w*B)^T [n][s]
    __shared__ float sw[64];

    if (tid < 64) {
        const float nAinv = -expf(-A_log[h]);
        float lav = 0.f;
        if (tid < len) lav = lab[(rowbase + tid) * NHEADS + h];
        float dtv = lav * nAinv;
        float v = lav;
#pragma unroll
        for (int off = 1; off < 64; off <<= 1) {
            float nb = __shfl_up(v, off);
            if (lane >= off) v += nb;
        }
        float last = __shfl(v, 63);
        sw[tid] = expf(last - v) * dtv;
        if (tid == 63) atot[blk] = expf(last);
    }
    __syncthreads();

    {
        const int r = tid >> 2, qq = tid & 3;
        const bf16x8 zz = {0,0,0,0,0,0,0,0};
        bf16x8 b0 = zz, b1 = zz, x0 = zz, x1 = zz;
        if (r < len) {
            const short* row = convo + (rowbase + r) * CONVDIM;
            b0 = *(const bf16x8*)&row[1024 + qq*16];
            b1 = *(const bf16x8*)&row[1024 + qq*16 + 8];
            x0 = *(const bf16x8*)&row[h*64 + qq*16];
            x1 = *(const bf16x8*)&row[h*64 + qq*16 + 8];
        }
        const float wsc = sw[r];
        short bs[16], xs[16];
        *(bf16x8*)&bs[0] = b0; *(bf16x8*)&bs[8] = b1;
        *(bf16x8*)&xs[0] = x0; *(bf16x8*)&xs[8] = x1;
#pragma unroll
        for (int i = 0; i < 16; i++) Xt[qq*16+i][r] = xs[i];
#pragma unroll
        for (int i = 0; i < 16; i++) Bw[qq*16+i][r] = f2bf(bf2f(bs[i]) * wsc);
    }
    __syncthreads();

    const int arow = (wave << 4) + (lane & 15);
    const int koff = (lane >> 4) << 3;
    const int trow0 = (wave << 4) + ((lane >> 4) << 2);
    const int scol = lane & 15;

    f32x4 sacc[4];
#pragma unroll
    for (int j = 0; j < 4; j++) sacc[j] = (f32x4){0.f,0.f,0.f,0.f};
    {
        bf16x8 a0 = *(const bf16x8*)&Xt[arow][koff];
        bf16x8 a1 = *(const bf16x8*)&Xt[arow][32 + koff];
#pragma unroll
        for (int j = 0; j < 4; j++) {
            const int brow = (j << 4) + (lane & 15);
            bf16x8 b0 = *(const bf16x8*)&Bw[brow][koff];
            bf16x8 b1 = *(const bf16x8*)&Bw[brow][32 + koff];
            sacc[j] = MFMA(a0, b0, sacc[j]);
            sacc[j] = MFMA(a1, b1, sacc[j]);
        }
    }
    const size_t sbase = (size_t)blk * 4096;
#pragma unroll
    for (int j = 0; j < 4; j++) {
        int n = j * 16 + scol;
#pragma unroll
        for (int i = 0; i < 4; i++) {
            int p = trow0 + i;
            Sbf[sbase + p * 64 + n] = f2bf(sacc[j][i]);
        }
    }
}

// ------- Phase B: scan over bf16 chunk states; 2 elements/thread, 4B access -------
__global__ __launch_bounds__(256) void chunk_state_scan_kernel(
    const short* __restrict__ Sbf, const float* __restrict__ atot,
    short* __restrict__ Hbf)
{
    int e = blockIdx.x * 256 + threadIdx.x;       // 64*2048 element-pairs
    int bh = e >> 11;
    int el = (e & 2047) * 2;
    int b = bh >> 4, h = bh & 15;
    float H0 = 0.f, H1 = 0.f;
    for (int c = 0; c < NCHUNK; c++) {
        int blk = (b * NCHUNK + c) * NHEADS + h;
        size_t off = (size_t)blk * 4096 + el;
        unsigned sv = *(const unsigned*)&Sbf[off];
        unsigned hv = (unsigned)(unsigned short)f2bf(H0) |
                      ((unsigned)(unsigned short)f2bf(H1) << 16);
        *(unsigned*)&Hbf[off] = hv;
        float at = atot[blk];
        H0 = at * H0 + bf2f_lo(sv);
        H1 = at * H1 + bf2f_hi(sv);
    }
}

// ------- Phase C: Y = (E_masked @ X) + exp(cum_t)*(C @ Hprev^T) + D*x -> bf16 -------
__global__ __launch_bounds__(256) void chunk_yfuse_kernel(
    const short* __restrict__ convo,
    const float* __restrict__ lab,
    const float* __restrict__ A_log,
    const float* __restrict__ D_skip,
    const short* __restrict__ Hbf,
    short* __restrict__ ybf)
{
    const int blk = blockIdx.x;
    const int h  = blk & 15;
    const int bc = blk >> 4;
    const int c  = bc & (NCHUNK - 1);
    const int b  = bc >> 5;
    const int t0 = c * Q;
    const int len = min(Q, SEQ - t0);
    const int tid = threadIdx.x;
    const int wave = tid >> 6, lane = tid & 63;
    const size_t rowbase = (size_t)b * SEQ + t0;

    __shared__ short Ct[64][72];    // C [t][n]; reused as E [t][s]
    __shared__ short Bt2[64][72];   // B [s][n]
    __shared__ short Xt[64][72];    // x^T [p][s]
    __shared__ short Hs[64][72];    // Hprev [p][n]
    __shared__ float cum[64], sdt[64];

    if (tid < 64) {
        const float nAinv = -expf(-A_log[h]);
        float lav = 0.f;
        if (tid < len) lav = lab[(rowbase + tid) * NHEADS + h];
        float dtv = lav * nAinv;
        float v = lav;
#pragma unroll
        for (int off = 1; off < 64; off <<= 1) {
            float nb = __shfl_up(v, off);
            if (lane >= off) v += nb;
        }
        cum[tid] = v; sdt[tid] = dtv;
    }
    __syncthreads();

    {
        const int r = tid >> 2, qq = tid & 3;
        const bf16x8 zz = {0,0,0,0,0,0,0,0};
        bf16x8 c0 = zz, c1 = zz, b0 = zz, b1 = zz, x0 = zz, x1 = zz;
        if (r < len) {
            const short* row = convo + (rowbase + r) * CONVDIM;
            c0 = *(const bf16x8*)&row[1088 + qq*16];
            c1 = *(const bf16x8*)&row[1088 + qq*16 + 8];
            b0 = *(const bf16x8*)&row[1024 + qq*16];
            b1 = *(const bf16x8*)&row[1024 + qq*16 + 8];
            x0 = *(const bf16x8*)&row[h*64 + qq*16];
            x1 = *(const bf16x8*)&row[h*64 + qq*16 + 8];
        }
        *(bf16x8*)&Ct[r][qq*16]    = c0; *(bf16x8*)&Ct[r][qq*16+8]  = c1;
        *(bf16x8*)&Bt2[r][qq*16]   = b0; *(bf16x8*)&Bt2[r][qq*16+8] = b1;
        short xs[16];
        *(bf16x8*)&xs[0] = x0; *(bf16x8*)&xs[8] = x1;
#pragma unroll
        for (int i = 0; i < 16; i++) Xt[qq*16+i][r] = xs[i];
        const size_t hbase = (size_t)blk * 4096;
        bf16x8 h0 = *(const bf16x8*)&Hbf[hbase + r*64 + qq*16];
        bf16x8 h1 = *(const bf16x8*)&Hbf[hbase + r*64 + qq*16 + 8];
        *(bf16x8*)&Hs[r][qq*16]   = h0;
        *(bf16x8*)&Hs[r][qq*16+8] = h1;
    }
    __syncthreads();

    const int arow = (wave << 4) + (lane & 15);
    const int koff = (lane >> 4) << 3;
    const int trow0 = (wave << 4) + ((lane >> 4) << 2);
    const int scol = lane & 15;

    // E = C.B^T and I = C.H^T (both A=Ct)
    f32x4 eacc[4], iacc[4];
#pragma unroll
    for (int j = 0; j < 4; j++) { eacc[j] = (f32x4){0.f,0.f,0.f,0.f}; iacc[j] = (f32x4){0.f,0.f,0.f,0.f}; }
    {
        bf16x8 a0 = *(const bf16x8*)&Ct[arow][koff];
        bf16x8 a1 = *(const bf16x8*)&Ct[arow][32 + koff];
#pragma unroll
        for (int j = 0; j < 4; j++) {
            const int brow = (j << 4) + (lane & 15);
            bf16x8 b0 = *(const bf16x8*)&Bt2[brow][koff];
            bf16x8 b1 = *(const bf16x8*)&Bt2[brow][32 + koff];
            eacc[j] = MFMA(a0, b0, eacc[j]);
            eacc[j] = MFMA(a1, b1, eacc[j]);
            bf16x8 h0 = *(const bf16x8*)&Hs[brow][koff];
            bf16x8 h1 = *(const bf16x8*)&Hs[brow][32 + koff];
            iacc[j] = MFMA(a0, h0, iacc[j]);
            iacc[j] = MFMA(a1, h1, iacc[j]);
        }
    }
    short ebf[4][4];
#pragma unroll
    for (int j = 0; j < 4; j++) {
        int s = j * 16 + scol;
#pragma unroll
        for (int i = 0; i < 4; i++) {
            int t = trow0 + i;
            float val = 0.f;
            if (s <= t) val = eacc[j][i] * expf(cum[t] - cum[s]) * sdt[s];
            ebf[j][i] = f2bf(val);
        }
    }
    __syncthreads();
#pragma unroll
    for (int j = 0; j < 4; j++)
#pragma unroll
        for (int i = 0; i < 4; i++)
            Ct[trow0 + i][j * 16 + scol] = ebf[j][i];
    __syncthreads();

    // Y_intra = E @ X
    f32x4 yacc[4];
#pragma unroll
    for (int j = 0; j < 4; j++) yacc[j] = (f32x4){0.f,0.f,0.f,0.f};
    {
        bf16x8 a0 = *(const bf16x8*)&Ct[arow][koff];
        bf16x8 a1 = *(const bf16x8*)&Ct[arow][32 + koff];
#pragma unroll
        for (int j = 0; j < 4; j++) {
            const int brow = (j << 4) + (lane & 15);
            bf16x8 b0 = *(const bf16x8*)&Xt[brow][koff];
            bf16x8 b1 = *(const bf16x8*)&Xt[brow][32 + koff];
            yacc[j] = MFMA(a0, b0, yacc[j]);
            yacc[j] = MFMA(a1, b1, yacc[j]);
        }
    }
    const float dsk = D_skip[h];
#pragma unroll
    for (int j = 0; j < 4; j++) {
        int p = j * 16 + scol;
#pragma unroll
        for (int i = 0; i < 4; i++) {
            int t = trow0 + i;
            if (t < len) {
                float ce = expf(cum[t]);
                float xv = bf2f(Xt[p][t]);
                float val = yacc[j][i] + ce * iacc[j][i] + dsk * xv;
                ybf[(rowbase + t) * DINNER + h * 64 + p] = f2bf(val);
            }
        }
    }
}

// ------------- gate with silu(z) + RMSNorm; vectorized short4 access -------------
__global__ __launch_bounds__(256) void gate_rmsnorm_kernel(short* __restrict__ y,
                                                           const short* __restrict__ zxb,
                                                           const float* __restrict__ norm_w) {
    const int m = blockIdx.x;
    const int tid = threadIdx.x;
    const int c = tid * 4;
    short4v yv = *(const short4v*)&y[(size_t)m * DINNER + c];
    short4v zv = *(const short4v*)&zxb[(size_t)m * ZW + c];
    float vals[4];
    float ss = 0.f;
#pragma unroll
    for (int i = 0; i < 4; i++) {
        float v = bf2f(yv[i]);
        float z = bf2f(zv[i]);
        float g = v * (z / (1.f + expf(-z)));
        vals[i] = g;
        ss += g * g;
    }
#pragma unroll
    for (int mask = 1; mask < 64; mask <<= 1) ss += __shfl_xor(ss, mask);
    __shared__ float red[4];
    if ((tid & 63) == 0) red[tid >> 6] = ss;
    __syncthreads();
    float tot = red[0] + red[1] + red[2] + red[3];
    float scale = rsqrtf(tot / 1024.f + 1e-5f);
    short4v ov;
#pragma unroll
    for (int i = 0; i < 4; i++) ov[i] = f2bf(vals[i] * scale * norm_w[c + i]);
    *(short4v*)&y[(size_t)m * DINNER + c] = ov;
}

extern "C" void kernel_launch(void* const* d_in, const int* in_sizes, int n_in,
                              void* d_out, int out_size, void* d_ws, size_t ws_size,
                              hipStream_t stream) {
    const float* x          = (const float*)d_in[0];
    const float* in_proj_w  = (const float*)d_in[1];
    const float* conv_w     = (const float*)d_in[2];
    const float* conv_b     = (const float*)d_in[3];
    const float* dt_bias    = (const float*)d_in[4];
    const float* A_log      = (const float*)d_in[5];
    const float* D_skip     = (const float*)d_in[6];
    const float* norm_w     = (const float*)d_in[7];
    const float* out_proj_w = (const float*)d_in[8];
    float* out = (float*)d_out;

    short* zxb   = (short*)d_ws;                              // NROWS*ZW bf16
    short* convo = zxb + (size_t)NROWS * ZW;                  // NROWS*CONVDIM bf16
    short* ybf   = convo + (size_t)NROWS * CONVDIM;           // NROWS*1024 bf16
    short* Hbf   = ybf + (size_t)NROWS * DINNER;              // 2048*4096 bf16
    short* Sbf   = Hbf + (size_t)2048 * 4096;                 // 2048*4096 bf16
    float* lab   = (float*)(Sbf + (size_t)2048 * 4096);       // NROWS*16 f32
    float* atotb = lab + (size_t)NROWS * NHEADS;              // 2048 f32
    short* w2t   = (short*)(atotb + 2048);                    // [512][1024] bf16
    // transient aliases (dead before hosts written):
    short* xb  = convo;                                       // NROWS*512 bf16, dead after K1
    short* w1t = xb + (size_t)NROWS * DMODEL;                 // 2192*512 bf16, dead after K1

    // prep
    convert_bf16_kernel<<<(NROWS * DMODEL / 8 + 255) / 256, 256, 0, stream>>>(x, xb, NROWS * DMODEL / 8);
    {
        dim3 g((DINPROJ + 63) / 64, (DMODEL + 63) / 64);
        transpose_cvt_kernel<<<g, 256, 0, stream>>>(in_proj_w, w1t, DMODEL, DINPROJ, DINPROJ);
    }
    {
        dim3 g((DMODEL + 63) / 64, (DINNER + 63) / 64);
        transpose_cvt_kernel<<<g, 256, 0, stream>>>(out_proj_w, w2t, DINNER, DMODEL, DMODEL);
    }

    // K1: in_proj GEMM (64x64, A gload_lds + B from L2); cols <2176 -> bf16 zxb, >=2176 -> fp32 la
    {
        dim3 g((NROWS + 63) / 64, (DINPROJ + 63) / 64);       // 128 x 35
        gemm_bf16<true><<<g, 256, 0, stream>>>(xb, w1t, zxb, NROWS, DINPROJ, DMODEL,
                                               ZW, lab, dt_bias, A_log);
    }

    // K2: conv + silu (bf16 in/out, 2 channels/thread)
    {
        int tot = BATCH * (SEQ / 4) * (CONVDIM / 2);
        conv_silu_kernel<<<(tot + 255) / 256, 256, 0, stream>>>(zxb, conv_w, conv_b, convo);
    }

    // K3a: chunk states (bf16)
    chunk_state_kernel<<<BATCH * NCHUNK * NHEADS, 256, 0, stream>>>(
        convo, lab, A_log, Sbf, atotb);

    // K3b: inter-chunk recurrence -> bf16 Hprev (2 elems/thread)
    chunk_state_scan_kernel<<<(64 * 2048) / 256, 256, 0, stream>>>(Sbf, atotb, Hbf);

    // K3c: fused intra + inter + D-skip -> bf16 y
    chunk_yfuse_kernel<<<BATCH * NCHUNK * NHEADS, 256, 0, stream>>>(
        convo, lab, A_log, D_skip, Hbf, ybf);

    // K4: gate + rmsnorm (in place, bf16, vectorized)
    gate_rmsnorm_kernel<<<NROWS, 256, 0, stream>>>(ybf, zxb, norm_w);

    // K5: out = ybf @ out_proj_w (64x64, A gload_lds + B from L2)
    {
        dim3 g((NROWS + 63) / 64, (DMODEL + 63) / 64);        // 128 x 8
        gemm_bf16<false><<<g, 256, 0, stream>>>(ybf, w2t, out, NROWS, DMODEL, DINNER,
                                                DMODEL, nullptr, nullptr, nullptr);
    }
}

// Round 16
// 139.875 us; speedup vs baseline: 2.1153x; 2.1153x over previous
//
#include <hip/hip_runtime.h>
#include <hip/hip_bf16.h>
#include <math.h>
#include <string.h>

#define BATCH   4
#define SEQ     2044
#define DMODEL  512
#define DINNER  1024
#define NHEADS  16
#define HEADDIM 64
#define DSTATE  64
#define CONVDIM 1152
#define DINPROJ 2192
#define ZW      2176          // bf16-stored width of zxbcdt (z + xBC); dt cols -> fp32 lab
#define NROWS   (BATCH*SEQ)   // 8176
#define Q       64
#define NCHUNK  32

typedef __attribute__((ext_vector_type(8))) short bf16x8;
typedef __attribute__((ext_vector_type(4))) short short4v;
typedef __attribute__((ext_vector_type(4))) float f32x4;

#define MFMA(a,b,c) __builtin_amdgcn_mfma_f32_16x16x32_bf16((a),(b),(c),0,0,0)

__device__ inline short f2bf(float f) {
    __hip_bfloat16 h = __float2bfloat16(f);
    short s; memcpy(&s, &h, 2); return s;
}
__device__ inline float bf2f(short s) {
    unsigned u = ((unsigned)(unsigned short)s) << 16;
    float f; memcpy(&f, &u, 4); return f;
}
__device__ inline float bf2f_lo(unsigned u) {
    unsigned v = u << 16; float f; memcpy(&f, &v, 4); return f;
}
__device__ inline float bf2f_hi(unsigned u) {
    unsigned v = u & 0xffff0000u; float f; memcpy(&f, &v, 4); return f;
}

// async global->LDS, 16B per lane; LDS dest = wave-uniform base + lane*16
__device__ __forceinline__ void gload16(const short* g, short* l) {
    __builtin_amdgcn_global_load_lds(
        (const __attribute__((address_space(1))) void*)g,
        (__attribute__((address_space(3))) void*)l, 16, 0, 0);
}

// ---------------- elementwise fp32 -> bf16 convert (8/thread) ----------------
__global__ __launch_bounds__(256) void convert_bf16_kernel(const float* __restrict__ in,
                                                           short* __restrict__ out, int n8) {
    int i = blockIdx.x * 256 + threadIdx.x;
    if (i >= n8) return;
    float4 v0 = *((const float4*)in + i * 2);
    float4 v1 = *((const float4*)in + i * 2 + 1);
    short t[8];
    t[0]=f2bf(v0.x); t[1]=f2bf(v0.y); t[2]=f2bf(v0.z); t[3]=f2bf(v0.w);
    t[4]=f2bf(v1.x); t[5]=f2bf(v1.y); t[6]=f2bf(v1.z); t[7]=f2bf(v1.w);
    *((bf16x8*)out + i) = *(const bf16x8*)t;
}

// ------- transpose + convert: in fp32 [R][ldi] -> out bf16 [Cc][R] -------
__global__ __launch_bounds__(256) void transpose_cvt_kernel(const float* __restrict__ in,
                                                            short* __restrict__ out,
                                                            int R, int Cc, int ldi) {
    __shared__ float tile[64][65];
    const int bx = blockIdx.x * 64;
    const int by = blockIdx.y * 64;
    const int tid = threadIdx.x;
#pragma unroll
    for (int i = 0; i < 16; i++) {
        int idx = tid + i * 256; int r = idx >> 6, c = idx & 63;
        float v = 0.f;
        if (by + r < R && bx + c < Cc) v = in[(size_t)(by + r) * ldi + bx + c];
        tile[r][c] = v;
    }
    __syncthreads();
#pragma unroll
    for (int i = 0; i < 16; i++) {
        int idx = tid + i * 256; int c = idx >> 6, r = idx & 63;
        if (bx + c < Cc && by + r < R)
            out[(size_t)(bx + c) * R + by + r] = f2bf(tile[r][c]);
    }
}

// ---- bf16 MFMA GEMM, 64x64 tile, BK=64, single-buffer gload_lds + XOR swizzle ----
// (R10/R14's proven geometry: 16KB LDS, ~8 blocks/CU.)
// LDS linear [64][64] shorts; 16B slot s of row r holds global col16 (s ^ (r&7)).
// Write side: lane l fetches global col16 (l&7)^(l>>3) of its row -> linear DMA dest.
// Epilogue: dt columns (gn >= Nbf) handled only in the last N-block (block-level branch).
template<bool BF16OUT>
__global__ __launch_bounds__(256) void gemm_bf16(const short* __restrict__ A,
                                                 const short* __restrict__ Bt,
                                                 void* __restrict__ Cv,
                                                 int M, int N, int K,
                                                 int Nbf, float* __restrict__ dtout,
                                                 const float* __restrict__ dt_bias,
                                                 const float* __restrict__ A_log) {
    __shared__ short As[64][64];
    __shared__ short Bs[64][64];
    const int tid = threadIdx.x;
    const int wave = tid >> 6, lane = tid & 63;
    const int bm = blockIdx.x * 64, bn = blockIdx.y * 64;
    const int lane15 = lane & 15;
    const int kgrp = lane >> 4;               // 0..3: which 8-short k-chunk
    const int srow = lane >> 3;               // 0..7: row within 8-row DMA group
    const int scol = (lane & 7) ^ srow;       // pre-swizzled source 16B slot
    const int r7 = lane15 & 7;

    f32x4 acc[4];
#pragma unroll
    for (int j = 0; j < 4; j++) acc[j] = (f32x4){0.f, 0.f, 0.f, 0.f};

    // per-lane global sources; wave w stages rows w*16..w*16+15 of each tile
    const short* Ab = A + (size_t)(bm + wave * 16 + srow) * K + scol * 8;
    const short* Bb = Bt + (size_t)(bn + wave * 16 + srow) * K + scol * 8;

    for (int kk = 0; kk < K; kk += 64) {
        gload16(Ab + kk,                 &As[wave * 16][0]);
        gload16(Ab + 8 * (size_t)K + kk, &As[wave * 16 + 8][0]);
        gload16(Bb + kk,                 &Bs[wave * 16][0]);
        gload16(Bb + 8 * (size_t)K + kk, &Bs[wave * 16 + 8][0]);
        __syncthreads();   // compiler drains vmcnt before barrier -> tiles ready
        const int arow = (wave << 4) + lane15;
        bf16x8 a0 = *(const bf16x8*)&As[arow][(kgrp ^ r7) * 8];
        bf16x8 a1 = *(const bf16x8*)&As[arow][((kgrp + 4) ^ r7) * 8];
#pragma unroll
        for (int j = 0; j < 4; j++) {
            const int brow = (j << 4) + lane15;
            bf16x8 b0 = *(const bf16x8*)&Bs[brow][(kgrp ^ r7) * 8];
            bf16x8 b1 = *(const bf16x8*)&Bs[brow][((kgrp + 4) ^ r7) * 8];
            acc[j] = MFMA(a0, b0, acc[j]);
            acc[j] = MFMA(a1, b1, acc[j]);
        }
        __syncthreads();   // all waves done reading before next tile overwrites
    }
    const int crow = bm + (wave << 4) + ((lane >> 4) << 2);
    const int ccol0 = bn + lane15;
    const bool has_dt = BF16OUT && (dtout != nullptr) && (bn + 64 > Nbf);
    if (!has_dt) {
        // clean path: all columns regular output
#pragma unroll
        for (int j = 0; j < 4; j++) {
            int gn = ccol0 + j * 16;
            if (gn >= N) continue;
#pragma unroll
            for (int i = 0; i < 4; i++) {
                int gm = crow + i;
                if (gm >= M) continue;
                float v = acc[j][i];
                if (BF16OUT) ((short*)Cv)[(size_t)gm * Nbf + gn] = f2bf(v);
                else         ((float*)Cv)[(size_t)gm * N + gn] = v;
            }
        }
    } else {
        const int ndt = N - Nbf;
#pragma unroll
        for (int j = 0; j < 4; j++) {
            int gn = ccol0 + j * 16;
            if (gn >= N) continue;
#pragma unroll
            for (int i = 0; i < 4; i++) {
                int gm = crow + i;
                if (gm >= M) continue;
                float v = acc[j][i];
                if (gn >= Nbf) {
                    int h = gn - Nbf;
                    float v2 = v + dt_bias[h];
                    float sp = (v2 > 20.f) ? v2 : log1pf(expf(v2));
                    dtout[(size_t)gm * ndt + h] = sp * (-expf(A_log[h]));
                } else {
                    ((short*)Cv)[(size_t)gm * Nbf + gn] = f2bf(v);
                }
            }
        }
    }
}

// -------- depthwise causal conv (k=4) + bias + SiLU; 2 channels/thread, 4B loads --------
__global__ __launch_bounds__(256) void conv_silu_kernel(const short* __restrict__ zxb,
                                                        const float* __restrict__ conv_w,
                                                        const float* __restrict__ conv_b,
                                                        short* __restrict__ convo) {
    const int CH2 = CONVDIM / 2;   // 576 channel pairs
    int idx = blockIdx.x * 256 + threadIdx.x;
    if (idx >= BATCH * (SEQ/4) * CH2) return;
    int cpair = idx % CH2;
    int q = idx / CH2;
    int b = q / (SEQ/4);
    int t0 = (q % (SEQ/4)) * 4;
    int c = cpair * 2;
    const size_t base = ((size_t)b * SEQ + t0) * ZW + DINNER + c;
    float4 wv0 = *(const float4*)&conv_w[c * 4];
    float4 wv1 = *(const float4*)&conv_w[c * 4 + 4];
    float x0[7], x1[7];
#pragma unroll
    for (int i = 0; i < 7; i++) {
        int t = t0 - 3 + i;
        if (t >= 0) {
            unsigned u = *(const unsigned*)&zxb[base + (size_t)(i - 3) * ZW];
            x0[i] = bf2f_lo(u); x1[i] = bf2f_hi(u);
        } else { x0[i] = 0.f; x1[i] = 0.f; }
    }
    const float b0 = conv_b[c], b1 = conv_b[c + 1];
    const size_t obase = ((size_t)b * SEQ + t0) * CONVDIM + c;
#pragma unroll
    for (int i = 0; i < 4; i++) {
        float a0 = b0 + x0[i]*wv0.x + x0[i+1]*wv0.y + x0[i+2]*wv0.z + x0[i+3]*wv0.w;
        float a1 = b1 + x1[i]*wv1.x + x1[i+1]*wv1.y + x1[i+2]*wv1.z + x1[i+3]*wv1.w;
        float s0 = a0 / (1.f + expf(-a0));
        float s1 = a1 / (1.f + expf(-a1));
        unsigned o = (unsigned)(unsigned short)f2bf(s0) |
                     ((unsigned)(unsigned short)f2bf(s1) << 16);
        *(unsigned*)&convo[obase + (size_t)i * CONVDIM] = o;
    }
}

// ------------- Phase A: per-(b,chunk,head) chunk state S = (w x)^T B (bf16 out) -------------
__global__ __launch_bounds__(256) void chunk_state_kernel(
    const short* __restrict__ convo,
    const float* __restrict__ lab,
    const float* __restrict__ A_log,
    short* __restrict__ Sbf,
    float* __restrict__ atot)
{
    const int blk = blockIdx.x;
    const int h  = blk & 15;
    const int bc = blk >> 4;
    const int c  = bc & (NCHUNK - 1);
    const int b  = bc >> 5;
    const int t0 = c * Q;
    const int len = min(Q, SEQ - t0);
    const int tid = threadIdx.x;
    const int wave = tid >> 6, lane = tid & 63;
    const size_t rowbase = (size_t)b * SEQ + t0;

    __shared__ short Xt[64][72];    // x^T    [p][s]
    __shared__ short Bw[64][72];    // (w*B)^T [n][s]
    __shared__ float sw[64];

    if (tid < 64) {
        const float nAinv = -expf(-A_log[h]);
        float lav = 0.f;
        if (tid < len) lav = lab[(rowbase + tid) * NHEADS + h];
        float dtv = lav * nAinv;
        float v = lav;
#pragma unroll
        for (int off = 1; off < 64; off <<= 1) {
            float nb = __shfl_up(v, off);
            if (lane >= off) v += nb;
        }
        float last = __shfl(v, 63);
        sw[tid] = expf(last - v) * dtv;
        if (tid == 63) atot[blk] = expf(last);
    }
    __syncthreads();

    {
        const int r = tid >> 2, qq = tid & 3;
        const bf16x8 zz = {0,0,0,0,0,0,0,0};
        bf16x8 b0 = zz, b1 = zz, x0 = zz, x1 = zz;
        if (r < len) {
            const short* row = convo + (rowbase + r) * CONVDIM;
            b0 = *(const bf16x8*)&row[1024 + qq*16];
            b1 = *(const bf16x8*)&row[1024 + qq*16 + 8];
            x0 = *(const bf16x8*)&row[h*64 + qq*16];
            x1 = *(const bf16x8*)&row[h*64 + qq*16 + 8];
        }
        const float wsc = sw[r];
        short bs[16], xs[16];
        *(bf16x8*)&bs[0] = b0; *(bf16x8*)&bs[8] = b1;
        *(bf16x8*)&xs[0] = x0; *(bf16x8*)&xs[8] = x1;
#pragma unroll
        for (int i = 0; i < 16; i++) Xt[qq*16+i][r] = xs[i];
#pragma unroll
        for (int i = 0; i < 16; i++) Bw[qq*16+i][r] = f2bf(bf2f(bs[i]) * wsc);
    }
    __syncthreads();

    const int arow = (wave << 4) + (lane & 15);
    const int koff = (lane >> 4) << 3;
    const int trow0 = (wave << 4) + ((lane >> 4) << 2);
    const int scol = lane & 15;

    f32x4 sacc[4];
#pragma unroll
    for (int j = 0; j < 4; j++) sacc[j] = (f32x4){0.f,0.f,0.f,0.f};
    {
        bf16x8 a0 = *(const bf16x8*)&Xt[arow][koff];
        bf16x8 a1 = *(const bf16x8*)&Xt[arow][32 + koff];
#pragma unroll
        for (int j = 0; j < 4; j++) {
            const int brow = (j << 4) + (lane & 15);
            bf16x8 b0 = *(const bf16x8*)&Bw[brow][koff];
            bf16x8 b1 = *(const bf16x8*)&Bw[brow][32 + koff];
            sacc[j] = MFMA(a0, b0, sacc[j]);
            sacc[j] = MFMA(a1, b1, sacc[j]);
        }
    }
    const size_t sbase = (size_t)blk * 4096;
#pragma unroll
    for (int j = 0; j < 4; j++) {
        int n = j * 16 + scol;
#pragma unroll
        for (int i = 0; i < 4; i++) {
            int p = trow0 + i;
            Sbf[sbase + p * 64 + n] = f2bf(sacc[j][i]);
        }
    }
}

// ------- Phase B: scan over bf16 chunk states; 2 elements/thread, 4B access -------
__global__ __launch_bounds__(256) void chunk_state_scan_kernel(
    const short* __restrict__ Sbf, const float* __restrict__ atot,
    short* __restrict__ Hbf)
{
    int e = blockIdx.x * 256 + threadIdx.x;       // 64*2048 element-pairs
    int bh = e >> 11;
    int el = (e & 2047) * 2;
    int b = bh >> 4, h = bh & 15;
    float H0 = 0.f, H1 = 0.f;
    for (int c = 0; c < NCHUNK; c++) {
        int blk = (b * NCHUNK + c) * NHEADS + h;
        size_t off = (size_t)blk * 4096 + el;
        unsigned sv = *(const unsigned*)&Sbf[off];
        unsigned hv = (unsigned)(unsigned short)f2bf(H0) |
                      ((unsigned)(unsigned short)f2bf(H1) << 16);
        *(unsigned*)&Hbf[off] = hv;
        float at = atot[blk];
        H0 = at * H0 + bf2f_lo(sv);
        H1 = at * H1 + bf2f_hi(sv);
    }
}

// ------- Phase C: Y = (E_masked @ X) + exp(cum_t)*(C @ Hprev^T) + D*x -> bf16 -------
__global__ __launch_bounds__(256) void chunk_yfuse_kernel(
    const short* __restrict__ convo,
    const float* __restrict__ lab,
    const float* __restrict__ A_log,
    const float* __restrict__ D_skip,
    const short* __restrict__ Hbf,
    short* __restrict__ ybf)
{
    const int blk = blockIdx.x;
    const int h  = blk & 15;
    const int bc = blk >> 4;
    const int c  = bc & (NCHUNK - 1);
    const int b  = bc >> 5;
    const int t0 = c * Q;
    const int len = min(Q, SEQ - t0);
    const int tid = threadIdx.x;
    const int wave = tid >> 6, lane = tid & 63;
    const size_t rowbase = (size_t)b * SEQ + t0;

    __shared__ short Ct[64][72];    // C [t][n]; reused as E [t][s]
    __shared__ short Bt2[64][72];   // B [s][n]
    __shared__ short Xt[64][72];    // x^T [p][s]
    __shared__ short Hs[64][72];    // Hprev [p][n]
    __shared__ float cum[64], sdt[64];

    if (tid < 64) {
        const float nAinv = -expf(-A_log[h]);
        float lav = 0.f;
        if (tid < len) lav = lab[(rowbase + tid) * NHEADS + h];
        float dtv = lav * nAinv;
        float v = lav;
#pragma unroll
        for (int off = 1; off < 64; off <<= 1) {
            float nb = __shfl_up(v, off);
            if (lane >= off) v += nb;
        }
        cum[tid] = v; sdt[tid] = dtv;
    }
    __syncthreads();

    {
        const int r = tid >> 2, qq = tid & 3;
        const bf16x8 zz = {0,0,0,0,0,0,0,0};
        bf16x8 c0 = zz, c1 = zz, b0 = zz, b1 = zz, x0 = zz, x1 = zz;
        if (r < len) {
            const short* row = convo + (rowbase + r) * CONVDIM;
            c0 = *(const bf16x8*)&row[1088 + qq*16];
            c1 = *(const bf16x8*)&row[1088 + qq*16 + 8];
            b0 = *(const bf16x8*)&row[1024 + qq*16];
            b1 = *(const bf16x8*)&row[1024 + qq*16 + 8];
            x0 = *(const bf16x8*)&row[h*64 + qq*16];
            x1 = *(const bf16x8*)&row[h*64 + qq*16 + 8];
        }
        *(bf16x8*)&Ct[r][qq*16]    = c0; *(bf16x8*)&Ct[r][qq*16+8]  = c1;
        *(bf16x8*)&Bt2[r][qq*16]   = b0; *(bf16x8*)&Bt2[r][qq*16+8] = b1;
        short xs[16];
        *(bf16x8*)&xs[0] = x0; *(bf16x8*)&xs[8] = x1;
#pragma unroll
        for (int i = 0; i < 16; i++) Xt[qq*16+i][r] = xs[i];
        const size_t hbase = (size_t)blk * 4096;
        bf16x8 h0 = *(const bf16x8*)&Hbf[hbase + r*64 + qq*16];
        bf16x8 h1 = *(const bf16x8*)&Hbf[hbase + r*64 + qq*16 + 8];
        *(bf16x8*)&Hs[r][qq*16]   = h0;
        *(bf16x8*)&Hs[r][qq*16+8] = h1;
    }
    __syncthreads();

    const int arow = (wave << 4) + (lane & 15);
    const int koff = (lane >> 4) << 3;
    const int trow0 = (wave << 4) + ((lane >> 4) << 2);
    const int scol = lane & 15;

    // E = C.B^T and I = C.H^T (both A=Ct)
    f32x4 eacc[4], iacc[4];
#pragma unroll
    for (int j = 0; j < 4; j++) { eacc[j] = (f32x4){0.f,0.f,0.f,0.f}; iacc[j] = (f32x4){0.f,0.f,0.f,0.f}; }
    {
        bf16x8 a0 = *(const bf16x8*)&Ct[arow][koff];
        bf16x8 a1 = *(const bf16x8*)&Ct[arow][32 + koff];
#pragma unroll
        for (int j = 0; j < 4; j++) {
            const int brow = (j << 4) + (lane & 15);
            bf16x8 b0 = *(const bf16x8*)&Bt2[brow][koff];
            bf16x8 b1 = *(const bf16x8*)&Bt2[brow][32 + koff];
            eacc[j] = MFMA(a0, b0, eacc[j]);
            eacc[j] = MFMA(a1, b1, eacc[j]);
            bf16x8 h0 = *(const bf16x8*)&Hs[brow][koff];
            bf16x8 h1 = *(const bf16x8*)&Hs[brow][32 + koff];
            iacc[j] = MFMA(a0, h0, iacc[j]);
            iacc[j] = MFMA(a1, h1, iacc[j]);
        }
    }
    short ebf[4][4];
#pragma unroll
    for (int j = 0; j < 4; j++) {
        int s = j * 16 + scol;
#pragma unroll
        for (int i = 0; i < 4; i++) {
            int t = trow0 + i;
            float val = 0.f;
            if (s <= t) val = eacc[j][i] * expf(cum[t] - cum[s]) * sdt[s];
            ebf[j][i] = f2bf(val);
        }
    }
    __syncthreads();
#pragma unroll
    for (int j = 0; j < 4; j++)
#pragma unroll
        for (int i = 0; i < 4; i++)
            Ct[trow0 + i][j * 16 + scol] = ebf[j][i];
    __syncthreads();

    // Y_intra = E @ X
    f32x4 yacc[4];
#pragma unroll
    for (int j = 0; j < 4; j++) yacc[j] = (f32x4){0.f,0.f,0.f,0.f};
    {
        bf16x8 a0 = *(const bf16x8*)&Ct[arow][koff];
        bf16x8 a1 = *(const bf16x8*)&Ct[arow][32 + koff];
#pragma unroll
        for (int j = 0; j < 4; j++) {
            const int brow = (j << 4) + (lane & 15);
            bf16x8 b0 = *(const bf16x8*)&Xt[brow][koff];
            bf16x8 b1 = *(const bf16x8*)&Xt[brow][32 + koff];
            yacc[j] = MFMA(a0, b0, yacc[j]);
            yacc[j] = MFMA(a1, b1, yacc[j]);
        }
    }
    const float dsk = D_skip[h];
#pragma unroll
    for (int j = 0; j < 4; j++) {
        int p = j * 16 + scol;
#pragma unroll
        for (int i = 0; i < 4; i++) {
            int t = trow0 + i;
            if (t < len) {
                float ce = expf(cum[t]);
                float xv = bf2f(Xt[p][t]);
                float val = yacc[j][i] + ce * iacc[j][i] + dsk * xv;
                ybf[(rowbase + t) * DINNER + h * 64 + p] = f2bf(val);
            }
        }
    }
}

// ------------- gate with silu(z) + RMSNorm; vectorized short4 access -------------
__global__ __launch_bounds__(256) void gate_rmsnorm_kernel(short* __restrict__ y,
                                                           const short* __restrict__ zxb,
                                                           const float* __restrict__ norm_w) {
    const int m = blockIdx.x;
    const int tid = threadIdx.x;
    const int c = tid * 4;
    short4v yv = *(const short4v*)&y[(size_t)m * DINNER + c];
    short4v zv = *(const short4v*)&zxb[(size_t)m * ZW + c];
    float vals[4];
    float ss = 0.f;
#pragma unroll
    for (int i = 0; i < 4; i++) {
        float v = bf2f(yv[i]);
        float z = bf2f(zv[i]);
        float g = v * (z / (1.f + expf(-z)));
        vals[i] = g;
        ss += g * g;
    }
#pragma unroll
    for (int mask = 1; mask < 64; mask <<= 1) ss += __shfl_xor(ss, mask);
    __shared__ float red[4];
    if ((tid & 63) == 0) red[tid >> 6] = ss;
    __syncthreads();
    float tot = red[0] + red[1] + red[2] + red[3];
    float scale = rsqrtf(tot / 1024.f + 1e-5f);
    short4v ov;
#pragma unroll
    for (int i = 0; i < 4; i++) ov[i] = f2bf(vals[i] * scale * norm_w[c + i]);
    *(short4v*)&y[(size_t)m * DINNER + c] = ov;
}

extern "C" void kernel_launch(void* const* d_in, const int* in_sizes, int n_in,
                              void* d_out, int out_size, void* d_ws, size_t ws_size,
                              hipStream_t stream) {
    const float* x          = (const float*)d_in[0];
    const float* in_proj_w  = (const float*)d_in[1];
    const float* conv_w     = (const float*)d_in[2];
    const float* conv_b     = (const float*)d_in[3];
    const float* dt_bias    = (const float*)d_in[4];
    const float* A_log      = (const float*)d_in[5];
    const float* D_skip     = (const float*)d_in[6];
    const float* norm_w     = (const float*)d_in[7];
    const float* out_proj_w = (const float*)d_in[8];
    float* out = (float*)d_out;

    short* zxb   = (short*)d_ws;                              // NROWS*ZW bf16
    short* convo = zxb + (size_t)NROWS * ZW;                  // NROWS*CONVDIM bf16
    short* ybf   = convo + (size_t)NROWS * CONVDIM;           // NROWS*1024 bf16
    short* Hbf   = ybf + (size_t)NROWS * DINNER;              // 2048*4096 bf16
    short* Sbf   = Hbf + (size_t)2048 * 4096;                 // 2048*4096 bf16
    float* lab   = (float*)(Sbf + (size_t)2048 * 4096);       // NROWS*16 f32
    float* atotb = lab + (size_t)NROWS * NHEADS;              // 2048 f32
    short* w2t   = (short*)(atotb + 2048);                    // [512][1024] bf16
    // transient aliases (dead before hosts written):
    short* xb  = convo;                                       // NROWS*512 bf16, dead after K1
    short* w1t = xb + (size_t)NROWS * DMODEL;                 // 2192*512 bf16, dead after K1

    // prep
    convert_bf16_kernel<<<(NROWS * DMODEL / 8 + 255) / 256, 256, 0, stream>>>(x, xb, NROWS * DMODEL / 8);
    {
        dim3 g((DINPROJ + 63) / 64, (DMODEL + 63) / 64);
        transpose_cvt_kernel<<<g, 256, 0, stream>>>(in_proj_w, w1t, DMODEL, DINPROJ, DINPROJ);
    }
    {
        dim3 g((DMODEL + 63) / 64, (DINNER + 63) / 64);
        transpose_cvt_kernel<<<g, 256, 0, stream>>>(out_proj_w, w2t, DINNER, DMODEL, DMODEL);
    }

    // K1: in_proj GEMM (64x64, gload_lds); cols <2176 -> bf16 zxb, >=2176 -> fp32 la (fused)
    {
        dim3 g((NROWS + 63) / 64, (DINPROJ + 63) / 64);       // 128 x 35
        gemm_bf16<true><<<g, 256, 0, stream>>>(xb, w1t, zxb, NROWS, DINPROJ, DMODEL,
                                               ZW, lab, dt_bias, A_log);
    }

    // K2: conv + silu (bf16 in/out, 2 channels/thread)
    {
        int tot = BATCH * (SEQ / 4) * (CONVDIM / 2);
        conv_silu_kernel<<<(tot + 255) / 256, 256, 0, stream>>>(zxb, conv_w, conv_b, convo);
    }

    // K3a: chunk states (bf16)
    chunk_state_kernel<<<BATCH * NCHUNK * NHEADS, 256, 0, stream>>>(
        convo, lab, A_log, Sbf, atotb);

    // K3b: inter-chunk recurrence -> bf16 Hprev (2 elems/thread)
    chunk_state_scan_kernel<<<(64 * 2048) / 256, 256, 0, stream>>>(Sbf, atotb, Hbf);

    // K3c: fused intra + inter + D-skip -> bf16 y
    chunk_yfuse_kernel<<<BATCH * NCHUNK * NHEADS, 256, 0, stream>>>(
        convo, lab, A_log, D_skip, Hbf, ybf);

    // K4: gate + rmsnorm (in place, bf16, vectorized)
    gate_rmsnorm_kernel<<<NROWS, 256, 0, stream>>>(ybf, zxb, norm_w);

    // K5: out = ybf @ out_proj_w (64x64, gload_lds)
    {
        dim3 g((NROWS + 63) / 64, (DMODEL + 63) / 64);        // 128 x 8
        gemm_bf16<false><<<g, 256, 0, stream>>>(ybf, w2t, out, NROWS, DMODEL, DINNER,
                                                DMODEL, nullptr, nullptr, nullptr);
    }
}